// Round 3
// baseline (94.803 us; speedup 1.0000x reference)
//
#include <hip/hip_runtime.h>
#include <float.h>

// NearestCluster: per-batch NN argmin.
// coords1 [L1=4096, N=8, C=3] f32 (reference points)
// coords2 [L2=4096, N=8, C=3] f32 (query points)
// out int32: [L2*N] cluster idx (argmin over L1, per batch), then [L2*N] batch idx.
//
// Numerics: bit-exact replication of numpy f32 reference:
//   qq = (q0*q0 + q1*q1) + q2*q2          (round each op, no fma)
//   rr = (r0*r0 + r1*r1) + r2*r2
//   dot = ((q0*r0) + (q1*r1)) + (q2*r2)   (round each op, no fma)
//   d2 = (qq + rr) - 2*dot                (2*dot exact; single-round subtract
//                                          == __fmaf_rn(-2, dot, qq+rr))
// argmin ties -> lowest index (np.argmin first occurrence).
//
// R1: 32KB chunks, 4 blocks/CU — occupancy 28%, VALUBusy 64%, dur 44us.
//     Diagnosis: LDS-BW bound (8 B LDS/pair) + shallow ILP (2 chains).
// R2: 8 queries/thread, wave=64-lane group over refs (mod 64).
//     LDS 2 B/pair (268 MB total ~4us); 8 indep d2 chains/step hide ds latency.

typedef float v2f __attribute__((ext_vector_type(2)));

constexpr int kL1 = 4096, kL2 = 4096, kN = 8;
constexpr int kChunk = 2048;      // refs per LDS chunk -> 32 KB
constexpr int kQ = 8;             // queries per wave (per thread)
constexpr int kQPerBlock = 32;    // 4 waves x 8 queries

__global__ __launch_bounds__(256, 4)
void nearest_kernel(const float* __restrict__ c1, const float* __restrict__ c2,
                    int* __restrict__ out) {
#pragma clang fp contract(off)
  __shared__ float4 refs[kChunk];  // x, y, z, rr

  const int tid = threadIdx.x;
  const int n = blockIdx.y;
  const int wave = tid >> 6;    // 0..3
  const int lane = tid & 63;    // 0..63
  const int q0 = blockIdx.x * kQPerBlock + wave * kQ;

  // ---- Load 8 queries (same for all 64 lanes of the wave), np-rounded qq ----
  v2f qx[4], qy[4], qz[4], qq[4];
#pragma unroll
  for (int i = 0; i < 4; ++i) {
    const float* p0 = c2 + ((q0 + 2 * i) * kN + n) * 3;
    const float* p1 = c2 + ((q0 + 2 * i + 1) * kN + n) * 3;
    const float a0 = p0[0], a1 = p0[1], a2 = p0[2];
    const float b0 = p1[0], b1 = p1[1], b2 = p1[2];
    qx[i] = v2f{a0, b0};
    qy[i] = v2f{a1, b1};
    qz[i] = v2f{a2, b2};
    qq[i] = v2f{
        __fadd_rn(__fadd_rn(__fmul_rn(a0, a0), __fmul_rn(a1, a1)),
                  __fmul_rn(a2, a2)),
        __fadd_rn(__fadd_rn(__fmul_rn(b0, b0), __fmul_rn(b1, b1)),
                  __fmul_rn(b2, b2))};
  }

  v2f bd[4];
  int bi[kQ];
#pragma unroll
  for (int i = 0; i < 4; ++i) { bd[i] = v2f{FLT_MAX, FLT_MAX}; }
#pragma unroll
  for (int i = 0; i < kQ; ++i) { bi[i] = 0; }

  for (int chunk = 0; chunk < kL1 / kChunk; ++chunk) {
    __syncthreads();  // previous chunk's readers done before overwrite

    // ---- Stage chunk of coords1[:, n, :] into LDS with np-rounded rr ----
#pragma unroll
    for (int k = 0; k < kChunk / 256; ++k) {
      const int j = tid + 256 * k;
      const float* p = c1 + ((chunk * kChunk + j) * kN + n) * 3;
      const float r0 = p[0], r1 = p[1], r2 = p[2];
      const float rr = __fadd_rn(
          __fadd_rn(__fmul_rn(r0, r0), __fmul_rn(r1, r1)), __fmul_rn(r2, r2));
      refs[j] = make_float4(r0, r1, r2, rr);
    }
    __syncthreads();

    const int base = chunk * kChunk + lane;
    // 32 steps/chunk; each lane covers refs j = lane + 64*t. Unroll 2 so two
    // ds_read_b128 are in flight; 8 independent chains per ref hide latency.
#pragma unroll 2
    for (int t = 0; t < kChunk / 64; ++t) {
      const float4 r = refs[lane + 64 * t];
      const int j = base + 64 * t;
#pragma unroll
      for (int i = 0; i < 4; ++i) {
        const v2f m0 = qx[i] * r.x;
        const v2f m1 = qy[i] * r.y;
        const v2f s01 = m0 + m1;
        const v2f m2 = qz[i] * r.z;
        const v2f dot = s01 + m2;
        const v2f A = qq[i] + r.w;
        const float da = __fmaf_rn(-2.0f, dot.x, A.x);
        const float db = __fmaf_rn(-2.0f, dot.y, A.y);
        if (da < bd[i].x) { bd[i].x = da; bi[2 * i] = j; }
        if (db < bd[i].y) { bd[i].y = db; bi[2 * i + 1] = j; }
      }
    }
  }

  // ---- Cross-lane merge over the full wave (xor 1..32), tie -> lower index ----
  float d[kQ];
#pragma unroll
  for (int i = 0; i < 4; ++i) { d[2 * i] = bd[i].x; d[2 * i + 1] = bd[i].y; }

#pragma unroll
  for (int i = 0; i < kQ; ++i) {
#pragma unroll
    for (int m = 1; m <= 32; m <<= 1) {
      const float od = __shfl_xor(d[i], m);
      const int oi = __shfl_xor(bi[i], m);
      if (od < d[i] || (od == d[i] && oi < bi[i])) { d[i] = od; bi[i] = oi; }
    }
  }

  if (lane == 0) {
#pragma unroll
    for (int i = 0; i < kQ; ++i) {
      out[(q0 + i) * kN + n] = bi[i];
      out[kL2 * kN + (q0 + i) * kN + n] = n;
    }
  }
}

extern "C" void kernel_launch(void* const* d_in, const int* in_sizes, int n_in,
                              void* d_out, int out_size, void* d_ws, size_t ws_size,
                              hipStream_t stream) {
  const float* c1 = (const float*)d_in[0];
  const float* c2 = (const float*)d_in[1];
  int* out = (int*)d_out;
  dim3 grid(kL2 / kQPerBlock, kN);  // 128 x 8 = 1024 blocks
  nearest_kernel<<<grid, dim3(256), 0, stream>>>(c1, c2, out);
}

// Round 5
// 92.205 us; speedup vs baseline: 1.0282x; 1.0282x over previous
//
#include <hip/hip_runtime.h>
#include <float.h>

// NearestCluster: per-batch NN argmin.
// coords1 [L1=4096, N=8, C=3] f32 (reference points)
// coords2 [L2=4096, N=8, C=3] f32 (query points)
// out int32: [L2*N] cluster idx (argmin over L1, per batch), then [L2*N] batch idx.
//
// Numerics: bit-exact replication of numpy f32 reference:
//   qq = (q0*q0 + q1*q1) + q2*q2          (round each op, no fma)
//   rr = (r0*r0 + r1*r1) + r2*r2
//   dot = ((q0*r0) + (q1*r1)) + (q2*r2)   (round each op, no fma)
//   d2 = (qq + rr) - 2*dot  == fma(dot, -2, qq+rr)  (2*dot exact)
// argmin ties -> lowest index (np.argmin first occurrence).
//
// R2: 8 q/thread, wave-wide ref split — dur 47us; compiler scalarizes v2f.
// R3: inline-asm v_pk_* — FAILED to assemble: VOP3P src1 must be a VGPR PAIR
//     even when op_sel broadcasts its low half (v75 scalar was rejected).
// R4: broadcast via op_sel on pair operands (rxy/rzw from the b128 load).

typedef float v2f __attribute__((ext_vector_type(2)));

// -------- packed f32 helpers (VOP3P, dual-pipe, IEEE RNE per lane) ----------
// a * broadcast(b.lo)
__device__ __forceinline__ v2f pk_mul_lo(v2f a, v2f b) {
  v2f d;
  asm("v_pk_mul_f32 %0, %1, %2 op_sel:[0,0] op_sel_hi:[1,0]"
      : "=v"(d) : "v"(a), "v"(b));
  return d;
}
// a * broadcast(b.hi)
__device__ __forceinline__ v2f pk_mul_hi(v2f a, v2f b) {
  v2f d;
  asm("v_pk_mul_f32 %0, %1, %2 op_sel:[0,1] op_sel_hi:[1,1]"
      : "=v"(d) : "v"(a), "v"(b));
  return d;
}
// a + broadcast(b.hi)
__device__ __forceinline__ v2f pk_add_hi(v2f a, v2f b) {
  v2f d;
  asm("v_pk_add_f32 %0, %1, %2 op_sel:[0,1] op_sel_hi:[1,1]"
      : "=v"(d) : "v"(a), "v"(b));
  return d;
}
__device__ __forceinline__ v2f pk_add(v2f a, v2f b) {
  v2f d;
  asm("v_pk_add_f32 %0, %1, %2" : "=v"(d) : "v"(a), "v"(b));
  return d;
}
__device__ __forceinline__ v2f pk_fma(v2f a, v2f b, v2f c) {
  v2f d;
  asm("v_pk_fma_f32 %0, %1, %2, %3" : "=v"(d) : "v"(a), "v"(b), "v"(c));
  return d;
}

constexpr int kL1 = 4096, kL2 = 4096, kN = 8;
constexpr int kChunk = 2048;      // refs per LDS chunk -> 32 KB
constexpr int kQ = 8;             // queries per wave (per thread)
constexpr int kQPerBlock = 32;    // 4 waves x 8 queries

__global__ __launch_bounds__(256, 4)
void nearest_kernel(const float* __restrict__ c1, const float* __restrict__ c2,
                    int* __restrict__ out) {
#pragma clang fp contract(off)
  __shared__ v2f refs[kChunk * 2];  // per ref: {x,y}, {z,rr}

  const int tid = threadIdx.x;
  const int n = blockIdx.y;
  const int wave = tid >> 6;    // 0..3
  const int lane = tid & 63;    // 0..63
  const int q0 = blockIdx.x * kQPerBlock + wave * kQ;

  // ---- Load 8 queries (wave-uniform), np-rounded qq ----
  v2f qx[4], qy[4], qz[4], qq[4];
#pragma unroll
  for (int i = 0; i < 4; ++i) {
    const float* p0 = c2 + ((q0 + 2 * i) * kN + n) * 3;
    const float* p1 = c2 + ((q0 + 2 * i + 1) * kN + n) * 3;
    const float a0 = p0[0], a1 = p0[1], a2 = p0[2];
    const float b0 = p1[0], b1 = p1[1], b2 = p1[2];
    qx[i] = v2f{a0, b0};
    qy[i] = v2f{a1, b1};
    qz[i] = v2f{a2, b2};
    qq[i] = v2f{
        __fadd_rn(__fadd_rn(__fmul_rn(a0, a0), __fmul_rn(a1, a1)),
                  __fmul_rn(a2, a2)),
        __fadd_rn(__fadd_rn(__fmul_rn(b0, b0), __fmul_rn(b1, b1)),
                  __fmul_rn(b2, b2))};
  }

  const v2f cm2 = {-2.0f, -2.0f};

  v2f bd[4];
  int bi[kQ];
#pragma unroll
  for (int i = 0; i < 4; ++i) { bd[i] = v2f{FLT_MAX, FLT_MAX}; }
#pragma unroll
  for (int i = 0; i < kQ; ++i) { bi[i] = 0; }

  for (int chunk = 0; chunk < kL1 / kChunk; ++chunk) {
    __syncthreads();  // previous chunk's readers done before overwrite

    // ---- Stage chunk of coords1[:, n, :] into LDS with np-rounded rr ----
#pragma unroll
    for (int k = 0; k < kChunk / 256; ++k) {
      const int j = tid + 256 * k;
      const float* p = c1 + ((chunk * kChunk + j) * kN + n) * 3;
      const float r0 = p[0], r1 = p[1], r2 = p[2];
      const float rr = __fadd_rn(
          __fadd_rn(__fmul_rn(r0, r0), __fmul_rn(r1, r1)), __fmul_rn(r2, r2));
      refs[2 * j] = v2f{r0, r1};
      refs[2 * j + 1] = v2f{r2, rr};
    }
    __syncthreads();

    const int base = chunk * kChunk + lane;
    // Each lane covers refs j = lane + 64*t. Unroll 8: LDS reads with
    // immediate offsets pipeline ahead of the packed-math bodies.
#pragma unroll 8
    for (int t = 0; t < kChunk / 64; ++t) {
      const v2f rxy = refs[2 * (lane + 64 * t)];
      const v2f rzw = refs[2 * (lane + 64 * t) + 1];
      const int j = base + 64 * t;
#pragma unroll
      for (int i = 0; i < 4; ++i) {
        const v2f m0 = pk_mul_lo(qx[i], rxy);   // * r.x
        const v2f m1 = pk_mul_hi(qy[i], rxy);   // * r.y
        const v2f s01 = pk_add(m0, m1);
        const v2f m2 = pk_mul_lo(qz[i], rzw);   // * r.z
        const v2f dot = pk_add(s01, m2);
        const v2f A = pk_add_hi(qq[i], rzw);    // + rr
        const v2f d2 = pk_fma(dot, cm2, A);     // round(A - 2*dot), bit-exact
        if (d2.x < bd[i].x) { bd[i].x = d2.x; bi[2 * i] = j; }
        if (d2.y < bd[i].y) { bd[i].y = d2.y; bi[2 * i + 1] = j; }
      }
    }
  }

  // ---- Cross-lane merge over the full wave (xor 1..32), tie -> lower index ----
  float d[kQ];
#pragma unroll
  for (int i = 0; i < 4; ++i) { d[2 * i] = bd[i].x; d[2 * i + 1] = bd[i].y; }

#pragma unroll
  for (int i = 0; i < kQ; ++i) {
#pragma unroll
    for (int m = 1; m <= 32; m <<= 1) {
      const float od = __shfl_xor(d[i], m);
      const int oi = __shfl_xor(bi[i], m);
      if (od < d[i] || (od == d[i] && oi < bi[i])) { d[i] = od; bi[i] = oi; }
    }
  }

  if (lane == 0) {
#pragma unroll
    for (int i = 0; i < kQ; ++i) {
      out[(q0 + i) * kN + n] = bi[i];
      out[kL2 * kN + (q0 + i) * kN + n] = n;
    }
  }
}

extern "C" void kernel_launch(void* const* d_in, const int* in_sizes, int n_in,
                              void* d_out, int out_size, void* d_ws, size_t ws_size,
                              hipStream_t stream) {
  const float* c1 = (const float*)d_in[0];
  const float* c2 = (const float*)d_in[1];
  int* out = (int*)d_out;
  dim3 grid(kL2 / kQPerBlock, kN);  // 128 x 8 = 1024 blocks
  nearest_kernel<<<grid, dim3(256), 0, stream>>>(c1, c2, out);
}